// Round 1
// 233.607 us; speedup vs baseline: 1.1966x; 1.1966x over previous
//
#include <hip/hip_runtime.h>
#include <hip/hip_bf16.h>
#include <float.h>
#include <stdint.h>

#define NPT    4096
#define EMB    512
#define NH     8
#define HD     64
#define KSPLIT 32     // score k-range split: KRANGE = 128 (4 tiles of 32)

typedef __attribute__((ext_vector_type(8))) _Float16 f16x8;
typedef __attribute__((ext_vector_type(4))) float f32x4;
typedef uint32_t u32;

// low plane is stored scaled by 2^11 (exact) so it stays in fp16 normal range;
// recombine with s = hi_acc + lo_acc * 2^-11.
#define LO_SCALE 2048.0f
#define LO_INV   4.8828125e-4f   // 2^-11

// async global->LDS DMA, 16B/lane. LDS dest = wave-uniform base + lane*16.
__device__ __forceinline__ void async_ld16(const void* gsrc, void* ldst) {
    __builtin_amdgcn_global_load_lds(
        (const __attribute__((address_space(1))) u32*)gsrc,
        (__attribute__((address_space(3))) u32*)ldst, 16, 0, 0);
}

// fp16x2 split: a ~= h + l/2048, |err| <= 2^-22 |a|. 3-product GEMM drops
// l*l (~2^-22 per term, random sign) -> end-to-end error is fp32-accum-noise
// dominated, same regime as the fp32 reference.
__device__ __forceinline__ void split2(float a, unsigned short& h, unsigned short& l) {
    _Float16 fh = (_Float16)a;
    float r = (a - (float)fh) * LO_SCALE;
    _Float16 fl = (_Float16)r;
    h = *reinterpret_cast<unsigned short*>(&fh);
    l = *reinterpret_cast<unsigned short*>(&fl);
}

// ---------------------------------------------------------------------------
// 1) fused prep: y=0 split x; y=1..3 split W (granule-major); y=4 pack adj
//    into TRANSPOSED bitmask bits_t[kword(128)][q(4096)]
// ---------------------------------------------------------------------------
__global__ __launch_bounds__(256) void prep_kernel(const float* __restrict__ x,
                                                   const float* __restrict__ wq,
                                                   const float* __restrict__ wk,
                                                   const float* __restrict__ wv,
                                                   const int* __restrict__ adj,
                                                   unsigned short* __restrict__ xs,
                                                   unsigned short* __restrict__ wqs,
                                                   unsigned short* __restrict__ wks,
                                                   unsigned short* __restrict__ wvs,
                                                   unsigned* __restrict__ bits_t) {
    int y = blockIdx.y;
    size_t i = (size_t)blockIdx.x * 256 + threadIdx.x;
    if (y == 4) {                               // pack adj (reads coalesced)
        int q = (int)(i >> 7), w = (int)i & 127;
        const int4* p = (const int4*)(adj + (size_t)q * NPT + w * 32);
        unsigned m = 0;
#pragma unroll
        for (int j = 0; j < 8; ++j) {
            int4 v = p[j];
            m |= (v.x != 0 ? 1u : 0u) << (j * 4 + 0);
            m |= (v.y != 0 ? 1u : 0u) << (j * 4 + 1);
            m |= (v.z != 0 ? 1u : 0u) << (j * 4 + 2);
            m |= (v.w != 0 ? 1u : 0u) << (j * 4 + 3);
        }
        bits_t[(size_t)w * NPT + q] = m;        // transposed write (2 MB, cheap)
    } else if (y == 0) {
        const size_t PL = (size_t)NPT * EMB;
        float4 v = ((const float4*)x)[i];
        ushort4 h, l;
        split2(v.x, h.x, l.x);
        split2(v.y, h.y, l.y);
        split2(v.z, h.z, l.z);
        split2(v.w, h.w, l.w);
        ((ushort4*)xs)[i]        = h;
        ((ushort4*)(xs + PL))[i] = l;
    } else {
        const size_t WPL = 262144;
        if (i >= WPL / 4) return;
        const float* src = (y == 1) ? wq : (y == 2) ? wk : wv;
        unsigned short* dst = (y == 1) ? wqs : (y == 2) ? wks : wvs;
        float4 v = ((const float4*)src)[i];
        int e  = (int)(i >> 7);
        int k0 = ((int)i & 127) * 4;
        int ebk = e >> 6, el = e & 63;
        int kc = k0 >> 5, g = (k0 >> 3) & 3, dd = k0 & 7;
        size_t off = ((((size_t)ebk * 16 + kc) * 4 + g) * 64 + el) * 8 + dd;
        ushort4 h, l;
        split2(v.x, h.x, l.x);
        split2(v.y, h.y, l.y);
        split2(v.z, h.z, l.z);
        split2(v.w, h.w, l.w);
        *(ushort4*)(dst + off)       = h;
        *(ushort4*)(dst + WPL + off) = l;
    }
}

// ---------------------------------------------------------------------------
// 2) projections via fp16x2 3-product MFMA. Counted-vmcnt barrier (no drain).
//    Q2/K2 granule-major: [h][t32(128)][dg(8)][i32(32)][8shorts], 2 planes.
// ---------------------------------------------------------------------------
__global__ __launch_bounds__(256, 3) void gemm_mfma(const unsigned short* __restrict__ xs,
                                                    const unsigned short* __restrict__ wqs,
                                                    const unsigned short* __restrict__ wks,
                                                    const unsigned short* __restrict__ wvs,
                                                    unsigned short* __restrict__ Q2,
                                                    unsigned short* __restrict__ K2,
                                                    float* __restrict__ V) {
    const int z = blockIdx.z;
    const unsigned short* W2 = (z == 0) ? wqs : (z == 1) ? wks : wvs;
    const size_t XPL = (size_t)NPT * EMB;
    const size_t WPL = 262144;
    const size_t OPL = (size_t)NH * NPT * HD;

    const int nb = blockIdx.x * 128;
    const int ebk = blockIdx.y;
    const int tid = threadIdx.x;
    const int wv = tid >> 6, lane = tid & 63;
    const int m = lane & 15, quad = lane >> 4;
    const int n0 = nb + wv * 32;

    __shared__ __align__(16) unsigned short Ws[2][2 * 2048];   // 2 x 8 KB

    auto prefetchW = [&](int kc, int buf) {     // 8 chunks: 2 per wave
#pragma unroll
        for (int i2 = 0; i2 < 2; ++i2) {
            int c = wv + 4 * i2;
            int p = c >> 2, sub = c & 3;
            const unsigned short* src = W2 + (size_t)p * WPL
                + ((size_t)ebk * 16 + kc) * 2048 + (sub * 64 + lane) * 8;
            async_ld16(src, &Ws[buf][p * 2048 + sub * 512]);
        }
    };
    f16x8 bfA[2][2], bfB[2][2];
    auto load_bf = [&](f16x8 (&bf)[2][2], int kc) {
#pragma unroll
        for (int nt = 0; nt < 2; ++nt)
#pragma unroll
            for (int p = 0; p < 2; ++p)
                bf[nt][p] = *(const f16x8*)(xs + (size_t)p * XPL
                    + (size_t)(n0 + nt * 16 + m) * EMB + kc * 32 + quad * 8);
    };

    f32x4 acc[2][4][2];                         // [plane-sum][mt][nt]
#pragma unroll
    for (int s = 0; s < 2; ++s)
#pragma unroll
        for (int mt = 0; mt < 4; ++mt)
#pragma unroll
            for (int nt = 0; nt < 2; ++nt) acc[s][mt][nt] = (f32x4){0.f, 0.f, 0.f, 0.f};

    prefetchW(0, 0);
    load_bf(bfA, 0);

    auto iter = [&](int kc, int buf, f16x8 (&cur)[2][2], f16x8 (&nxt)[2][2]) {
        // own 2 W-chunks done; 4 bf loads for this kc stay in flight
        asm volatile("s_waitcnt vmcnt(4)\n\ts_barrier" ::: "memory");
        if (kc < 15) { prefetchW(kc + 1, buf ^ 1); load_bf(nxt, kc + 1); }
#pragma unroll
        for (int ga = 0; ga < 2; ++ga) {        // ga = W plane
            f16x8 af[4];
#pragma unroll
            for (int mt = 0; mt < 4; ++mt)
                af[mt] = *(const f16x8*)&Ws[buf][ga * 2048 + (quad * 64 + mt * 16 + m) * 8];
#pragma unroll
            for (int pb = 0; pb < 2 - ga; ++pb) // products: hh, hl, lh
#pragma unroll
                for (int mt = 0; mt < 4; ++mt)
#pragma unroll
                    for (int nt = 0; nt < 2; ++nt)
                        acc[ga + pb][mt][nt] = __builtin_amdgcn_mfma_f32_16x16x32_f16(
                            af[mt], cur[nt][pb], acc[ga + pb][mt][nt], 0, 0, 0);
        }
    };

#pragma unroll 1
    for (int kc2 = 0; kc2 < 16; kc2 += 2) {
        iter(kc2, 0, bfA, bfB);
        iter(kc2 + 1, 1, bfB, bfA);
    }

    const int h = ebk;
#pragma unroll
    for (int mt = 0; mt < 4; ++mt)
#pragma unroll
        for (int nt = 0; nt < 2; ++nt) {
            const int n = n0 + nt * 16 + m;
            const int d0 = mt * 16 + quad * 4;
            f32x4 a;
#pragma unroll
            for (int j = 0; j < 4; ++j)
                a[j] = fmaf(acc[1][mt][nt][j], LO_INV, acc[0][mt][nt][j]);
            if (z == 2) {
                *(f32x4*)(V + (size_t)n * EMB + ebk * 64 + d0) = a;
            } else {
                ushort4 ph, pl;
                split2(a[0], ph.x, pl.x);
                split2(a[1], ph.y, pl.y);
                split2(a[2], ph.z, pl.z);
                split2(a[3], ph.w, pl.w);
                unsigned short* O2 = (z == 0) ? Q2 : K2;
                size_t off = ((size_t)h * 128 + (n >> 5)) * 2048
                           + (d0 >> 3) * 256 + (n & 31) * 8 + (d0 & 7);
                *(ushort4*)(O2 + off)       = ph;
                *(ushort4*)(O2 + OPL + off) = pl;
            }
        }
}

// ---------------------------------------------------------------------------
// 3) masked argmax via fp16x2 3-product MFMA (24 MFMA/tile vs 48 before).
//    Triple-buffered K tiles via global_load_lds, manual vmcnt(2)+s_barrier
//    (prefetch distance 2). Next head's Q issued at kst==3 (hidden latency).
// ---------------------------------------------------------------------------
__global__ __launch_bounds__(256, 4) void score_mfma(const unsigned short* __restrict__ Q2,
                                                     const unsigned short* __restrict__ K2,
                                                     const unsigned* __restrict__ bits_t,
                                                     float* __restrict__ pval,
                                                     int* __restrict__ pidx) {
    const int qb = blockIdx.x * 128;
    const int ks = blockIdx.y;
    const int tid = threadIdx.x;
    const int wv = tid >> 6, lane = tid & 63;
    const int m = lane & 15, quad = lane >> 4;
    const size_t PL = (size_t)NH * NPT * HD;
    const int kq = qb + wv * 32;

    __shared__ __align__(16) unsigned short Ks[3][2 * 2048];   // 3 x 8 KB

    auto prefetchK = [&](int t) {          // 2 DMA chunks per wave per tile
        int h = t >> 2, kt = ks * 4 + (t & 3), buf = t % 3;
#pragma unroll
        for (int i2 = 0; i2 < 2; ++i2) {
            int c = wv + 4 * i2;
            int p = c >> 2, sub = c & 3;
            const unsigned short* src = K2 + (size_t)p * PL
                + ((size_t)h * 128 + kt) * 2048 + (sub * 64 + lane) * 8;
            async_ld16(src, &Ks[buf][p * 2048 + sub * 512]);
        }
    };

    f16x8 qf[2][2][2];                     // [nt][dc][plane]
    auto load_qf = [&](int hh) {
#pragma unroll
        for (int nt = 0; nt < 2; ++nt)
#pragma unroll
            for (int dc = 0; dc < 2; ++dc)
#pragma unroll
                for (int p = 0; p < 2; ++p)
                    qf[nt][dc][p] = *(const f16x8*)(Q2 + (size_t)p * PL
                        + ((size_t)hh * 128 + (kq >> 5)) * 2048
                        + (dc * 4 + quad) * 256 + (nt * 16 + m) * 8);
    };

    load_qf(0);                            // oldest vmem ops (drained at t=0)
    prefetchK(0);
    prefetchK(1);

    float bestv[2]; int besti[2];

#pragma unroll 1
    for (int t = 0; t < NH * 4; ++t) {
        const int h = t >> 2, kst = t & 3, buf = t % 3;
        const int kbase = ks * 128 + kst * 32;

        // own tile's 2 chunks (+earlier qf) done; next tile's 2 stay in flight.
        asm volatile("s_waitcnt vmcnt(2)\n\ts_barrier" ::: "memory");

        if (kst == 0) { bestv[0] = bestv[1] = -FLT_MAX; besti[0] = besti[1] = 0; }

        unsigned bw[2];                    // coalesced: lanes -> consecutive q
#pragma unroll
        for (int nt = 0; nt < 2; ++nt)
            bw[nt] = bits_t[(size_t)(ks * 4 + kst) * NPT + kq + nt * 16 + m];

        f32x4 acc[2][2][2];                // [plane-sum][mt][nt]
#pragma unroll
        for (int s = 0; s < 2; ++s)
#pragma unroll
            for (int mt = 0; mt < 2; ++mt)
#pragma unroll
                for (int nt = 0; nt < 2; ++nt) acc[s][mt][nt] = (f32x4){0.f, 0.f, 0.f, 0.f};

#pragma unroll
        for (int ga = 0; ga < 2; ++ga) {   // ga = K plane
            f16x8 kf[2][2];
#pragma unroll
            for (int mt = 0; mt < 2; ++mt)
#pragma unroll
                for (int dc = 0; dc < 2; ++dc)
                    kf[mt][dc] = *(const f16x8*)
                        &Ks[buf][ga * 2048 + ((dc * 4 + quad) * 32 + mt * 16 + m) * 8];
#pragma unroll
            for (int pb = 0; pb < 2 - ga; ++pb)   // products: hh, hl, lh
#pragma unroll
                for (int dc = 0; dc < 2; ++dc)
#pragma unroll
                    for (int mt = 0; mt < 2; ++mt)
#pragma unroll
                        for (int nt = 0; nt < 2; ++nt)
                            acc[ga + pb][mt][nt] = __builtin_amdgcn_mfma_f32_16x16x32_f16(
                                kf[mt][dc], qf[nt][dc][pb], acc[ga + pb][mt][nt], 0, 0, 0);
        }

        // issue next head's Q right after its last use -> latency hidden
        if (kst == 3 && h + 1 < NH) load_qf(h + 1);
        if (t + 2 < NH * 4) prefetchK(t + 2);   // youngest loads

        // C: col=lane&15 -> q; row=quad*4+r -> k
#pragma unroll
        for (int nt = 0; nt < 2; ++nt) {
            unsigned w = bw[nt];
#pragma unroll
            for (int mt = 0; mt < 2; ++mt) {
                int k0 = mt * 16 + quad * 4;
                f32x4 a0 = acc[0][mt][nt], a1 = acc[1][mt][nt];
#pragma unroll
                for (int r = 0; r < 4; ++r) {
                    if ((w >> (k0 + r)) & 1u) {
                        float s = fmaf(a1[r], LO_INV, a0[r]);
                        if (s > bestv[nt]) { bestv[nt] = s; besti[nt] = kbase + k0 + r; }
                    }
                }
            }
        }

        if (kst == 3) {                    // end of head: reduce over quad groups
#pragma unroll
            for (int nt = 0; nt < 2; ++nt) {
                float v = bestv[nt]; int bi = besti[nt];
#pragma unroll
                for (int off = 16; off < 64; off <<= 1) {
                    float ov = __shfl_xor(v, off);
                    int   oi = __shfl_xor(bi, off);
                    if (ov > v || (ov == v && oi < bi)) { v = ov; bi = oi; }
                }
                if (quad == 0) {
                    size_t o = ((size_t)h * KSPLIT + ks) * NPT + kq + nt * 16 + m;
                    pval[o] = v; pidx[o] = bi;
                }
            }
        }
    }
}

// ---------------------------------------------------------------------------
// 4) reduce k-split partials, gather winner V row * (1/NH)
// ---------------------------------------------------------------------------
__global__ __launch_bounds__(128) void gather_out(const float* __restrict__ V,
                                                  const float* __restrict__ pval,
                                                  const int* __restrict__ pidx,
                                                  float* __restrict__ out) {
    const int q = blockIdx.x;
    const int tid = threadIdx.x;
    __shared__ int widx[NH];
    if (tid < NH) {
        float bv = -FLT_MAX; int bi = 0;
        for (int ks = 0; ks < KSPLIT; ++ks) {
            size_t off = ((size_t)tid * KSPLIT + ks) * NPT + q;
            float v = pval[off];
            if (v > bv) { bv = v; bi = pidx[off]; }
        }
        widx[tid] = bi;
    }
    __syncthreads();
    const int h = tid >> 4;
    const int d4 = (tid & 15) * 4;
    const int k = widx[h];
    float4 v = *(const float4*)(V + (size_t)k * EMB + h * HD + d4);
    v.x *= 0.125f; v.y *= 0.125f; v.z *= 0.125f; v.w *= 0.125f;
    *(float4*)(out + (size_t)q * EMB + h * HD + d4) = v;
}

// ---------------------------------------------------------------------------
extern "C" void kernel_launch(void* const* d_in, const int* in_sizes, int n_in,
                              void* d_out, int out_size, void* d_ws, size_t ws_size,
                              hipStream_t stream) {
    const float* x   = (const float*)d_in[0];
    const int*   adj = (const int*)d_in[1];
    const float* WQ  = (const float*)d_in[2];
    const float* WK  = (const float*)d_in[3];
    const float* WV  = (const float*)d_in[4];
    // we/be are dead: energy is constant along k -> argmax unchanged.
    float* out = (float*)d_out;

    char* ws = (char*)d_ws;
    const size_t HMB = 512u * 1024;
    unsigned short* xs   = (unsigned short*)(ws);                 // 8 MB (dead after gemm)
    unsigned short* wqs  = (unsigned short*)(ws + 16 * HMB);      // 1 MB
    unsigned short* wks  = (unsigned short*)(ws + 18 * HMB);
    unsigned short* wvs  = (unsigned short*)(ws + 20 * HMB);
    unsigned short* Q2   = (unsigned short*)(ws + 22 * HMB);      // 8 MB granule-major
    unsigned short* K2   = (unsigned short*)(ws + 38 * HMB);      // 8 MB granule-major
    float*          V    = (float*)(ws + 54 * HMB);               // 8 MB
    unsigned*       bits = (unsigned*)(ws + 70 * HMB);            // 2 MB transposed
    float*          pval = (float*)(ws);                          // 4 MB, aliases dead xs
    int*            pidx = (int*)(ws + 8 * HMB);                  // 4 MB, aliases dead xs

    prep_kernel<<<dim3(2048, 5), dim3(256), 0, stream>>>(x, WQ, WK, WV, adj,
                                                         xs, wqs, wks, wvs, bits);
    gemm_mfma<<<dim3(NPT / 128, NH, 3), dim3(256), 0, stream>>>(xs, wqs, wks, wvs, Q2, K2, V);
    score_mfma<<<dim3(NPT / 128, KSPLIT), dim3(256), 0, stream>>>(Q2, K2, bits, pval, pidx);
    gather_out<<<dim3(NPT), dim3(128), 0, stream>>>(V, pval, pidx, out);
}